// Round 2
// baseline (488.361 us; speedup 1.0000x reference)
//
#include <hip/hip_runtime.h>
#include <hip/hip_bf16.h>
#include <math.h>

#define S_LEN 4096
#define HID 768
#define NH 12
#define DH 64
#define MQKV 2304

// ---------------- RoPE cos/sin table: [4096][32] each ----------------
__global__ __launch_bounds__(256) void rope_table_kernel(
    const int* __restrict__ pos, float* __restrict__ cosT, float* __restrict__ sinT)
{
  int idx = blockIdx.x * 256 + threadIdx.x;
  if (idx >= S_LEN * 32) return;
  int s = idx >> 5, j = idx & 31;
  float p = (float)pos[s];
  float inv = 1.0f / powf(10000.0f, (float)(2 * j) / 64.0f);
  float ang = p * inv;
  cosT[idx] = (float)cos((double)ang);
  sinT[idx] = (float)sin((double)ang);
}

// ---------------- fp32 GEMM: C[m][n] = sum_k W[m][k]*X[k][n] ----------------
// W: [M][768] row-major, X: [768][4096], C: [M][4096]. Tile 64x64, K-step 16.
// Blocks with blockIdx.y < ropeTiles get the RoPE epilogue (tile rows = one head).
__global__ __launch_bounds__(256) void gemm_rope_kernel(
    const float* __restrict__ W, const float* __restrict__ X,
    float* __restrict__ C,
    const float* __restrict__ cosT, const float* __restrict__ sinT,
    int ropeTiles)
{
  __shared__ float smem[64 * 68];          // 17.4 KB, reused as C-tile in epilogue
  float* As = smem;                        // [16][68]  As[kk][m]
  float* Bs = smem + 16 * 68;              // [16][64]  Bs[kk][n]
  const int tid = threadIdx.x;
  const int tx = tid & 15, ty = tid >> 4;
  const int m0b = blockIdx.y * 64;
  const int n0b = blockIdx.x * 64;
  const int arow = tid >> 2, acol = (tid & 3) * 4;
  const int brow = tid >> 4, bcol = (tid & 15) * 4;
  float acc[4][4] = {};
  const float* wp = W + (m0b + arow) * 768 + acol;
  const float* xp = X + brow * 4096 + n0b + bcol;

  for (int k = 0; k < 768; k += 16) {
    float4 a4 = *(const float4*)(wp + k);
    float4 b4 = *(const float4*)(xp + (size_t)k * 4096);
    __syncthreads();
    As[(acol + 0) * 68 + arow] = a4.x;
    As[(acol + 1) * 68 + arow] = a4.y;
    As[(acol + 2) * 68 + arow] = a4.z;
    As[(acol + 3) * 68 + arow] = a4.w;
    *(float4*)&Bs[brow * 64 + bcol] = b4;
    __syncthreads();
#pragma unroll
    for (int kk = 0; kk < 16; ++kk) {
      float4 av = *(const float4*)&As[kk * 68 + ty * 4];
      float4 bv = *(const float4*)&Bs[kk * 64 + tx * 4];
      acc[0][0] += av.x * bv.x; acc[0][1] += av.x * bv.y; acc[0][2] += av.x * bv.z; acc[0][3] += av.x * bv.w;
      acc[1][0] += av.y * bv.x; acc[1][1] += av.y * bv.y; acc[1][2] += av.y * bv.z; acc[1][3] += av.y * bv.w;
      acc[2][0] += av.z * bv.x; acc[2][1] += av.z * bv.y; acc[2][2] += av.z * bv.z; acc[2][3] += av.z * bv.w;
      acc[3][0] += av.w * bv.x; acc[3][1] += av.w * bv.y; acc[3][2] += av.w * bv.z; acc[3][3] += av.w * bv.w;
    }
  }
  __syncthreads();
  float* Ct = smem;                        // [64][68]
#pragma unroll
  for (int i = 0; i < 4; ++i) {
    *(float4*)&Ct[(ty * 4 + i) * 68 + tx * 4] =
        make_float4(acc[i][0], acc[i][1], acc[i][2], acc[i][3]);
  }
  __syncthreads();
  const bool rope = (blockIdx.y < (unsigned)ropeTiles);
#pragma unroll
  for (int i = 0; i < 4; ++i) {
    int d = ty * 4 + i;
    float4 v = *(const float4*)&Ct[d * 68 + tx * 4];
    if (rope) {
      // q'[d] = q[d]*cos(p*inv[d%32]) + (d<32 ? -q[d+32] : q[d-32])*sin(...)
      float4 r = *(const float4*)&Ct[(d ^ 32) * 68 + tx * 4];
      float sgn = (d < 32) ? -1.f : 1.f;
      int fidx = d & 31;
      int sbase = n0b + tx * 4;
      float vv[4] = {v.x, v.y, v.z, v.w};
      float rr[4] = {r.x, r.y, r.z, r.w};
#pragma unroll
      for (int j = 0; j < 4; ++j) {
        float c  = cosT[(sbase + j) * 32 + fidx];
        float sn = sinT[(sbase + j) * 32 + fidx];
        vv[j] = vv[j] * c + sgn * rr[j] * sn;
      }
      v = make_float4(vv[0], vv[1], vv[2], vv[3]);
    }
    *(float4*)&C[(size_t)(m0b + d) * 4096 + n0b + tx * 4] = v;
  }
}

// ---------------- windowed attention ----------------
// qkv layout: [3][12][64][4096]  (q then k then v, each [head][dim][s])
// block = (head, 64-query tile); keys span 192 = 64 + 64 + 64
#define QB 64
#define KSPAN 192

__global__ __launch_bounds__(256) void attn_kernel(
    const float* __restrict__ qkv, const float* __restrict__ amask,
    float* __restrict__ attn_out)
{
  __shared__ float Qt[QB][68];       // 17.4 KB
  __shared__ float Kt[KSPAN][68];    // 52.2 KB (reused for V)
  __shared__ float P[QB][196];       // 50.2 KB
  __shared__ float red[QB][4];
  __shared__ float rowinv[QB];

  const int t = threadIdx.x;
  const int h = blockIdx.y;
  const int q0 = blockIdx.x * QB;
  const int kstart = q0 - 64;
  const float* qbase = qkv + (size_t)(h * 64) * 4096;
  const float* kbase = qkv + (size_t)(768 + h * 64) * 4096;
  const float* vbase = qkv + (size_t)(1536 + h * 64) * 4096;

  // load Q tile (transposed into [qi][d])
  for (int idx = t; idx < QB * 64; idx += 256) {
    int d = idx >> 6, qi = idx & 63;
    Qt[qi][d] = qbase[(size_t)d * 4096 + q0 + qi];
  }
  // load K tile [kk][d], zero outside sequence bounds
  for (int idx = t; idx < KSPAN * 64; idx += 256) {
    int d = idx / KSPAN, kk = idx - d * KSPAN;
    int key = kstart + kk;
    Kt[kk][d] = (key >= 0 && key < S_LEN) ? kbase[(size_t)d * 4096 + key] : 0.f;
  }
  __syncthreads();

  // scores: dense 64x192, -1e30 outside window (exp -> exactly 0)
  for (int idx = t; idx < QB * KSPAN; idx += 256) {
    int qi = idx / KSPAN, kk = idx - qi * KSPAN;
    int qq = q0 + qi, key = kstart + kk;
    float sc = -1e30f;
    if (key >= 0 && key < S_LEN && kk >= qi && kk <= qi + 128) {
      float4 s4 = make_float4(0.f, 0.f, 0.f, 0.f);
#pragma unroll
      for (int c = 0; c < 16; ++c) {
        float4 a = *(const float4*)&Qt[qi][4 * c];
        float4 b = *(const float4*)&Kt[kk][4 * c];
        s4.x += a.x * b.x; s4.y += a.y * b.y; s4.z += a.z * b.z; s4.w += a.w * b.w;
      }
      sc = (s4.x + s4.y + s4.z + s4.w) * 0.125f + amask[(size_t)qq * 4096 + key];
    }
    P[qi][kk] = sc;
  }
  __syncthreads();

  // softmax: 4 threads per row
  const int row = t >> 2, part = t & 3;
  float m = -1e30f;
  for (int kk = part * 48; kk < part * 48 + 48; ++kk) m = fmaxf(m, P[row][kk]);
  red[row][part] = m;
  __syncthreads();
  float rm = fmaxf(fmaxf(red[row][0], red[row][1]), fmaxf(red[row][2], red[row][3]));
  float sum = 0.f;
  for (int kk = part * 48; kk < part * 48 + 48; ++kk) {
    float e = expf(P[row][kk] - rm);
    P[row][kk] = e;
    sum += e;
  }
  __syncthreads();
  red[row][part] = sum;
  __syncthreads();
  if (part == 0)
    rowinv[row] = 1.f / (red[row][0] + red[row][1] + red[row][2] + red[row][3]);

  // load V over Kt
  for (int idx = t; idx < KSPAN * 64; idx += 256) {
    int d = idx / KSPAN, kk = idx - d * KSPAN;
    int key = kstart + kk;
    Kt[kk][d] = (key >= 0 && key < S_LEN) ? vbase[(size_t)d * 4096 + key] : 0.f;
  }
  __syncthreads();

  // PV: thread -> 4 queries (qg..qg+3) x 4 dims (dbase + 16*dl)
  const int qg = (t & 15) * 4;
  const int dbase = t >> 4;
  float accv[4][4] = {};
  const int kklo = qg;
  const int kkhi = min(qg + 131, KSPAN - 1);
  for (int kk = kklo; kk <= kkhi; ++kk) {
    float p0 = P[qg + 0][kk], p1 = P[qg + 1][kk], p2 = P[qg + 2][kk], p3 = P[qg + 3][kk];
#pragma unroll
    for (int dl = 0; dl < 4; ++dl) {
      float v = Kt[kk][dbase + dl * 16];
      accv[dl][0] += p0 * v; accv[dl][1] += p1 * v; accv[dl][2] += p2 * v; accv[dl][3] += p3 * v;
    }
  }
  float i0 = rowinv[qg + 0], i1 = rowinv[qg + 1], i2 = rowinv[qg + 2], i3 = rowinv[qg + 3];
#pragma unroll
  for (int dl = 0; dl < 4; ++dl) {
    int d = dbase + dl * 16;
    float4 o = make_float4(accv[dl][0] * i0, accv[dl][1] * i1, accv[dl][2] * i2, accv[dl][3] * i3);
    *(float4*)&attn_out[(size_t)(h * 64 + d) * 4096 + q0 + qg] = o;
  }
}

extern "C" void kernel_launch(void* const* d_in, const int* in_sizes, int n_in,
                              void* d_out, int out_size, void* d_ws, size_t ws_size,
                              hipStream_t stream) {
  const float* x      = (const float*)d_in[0];
  const int* pos      = (const int*)d_in[1];   // integer inputs arrive as int32
  const float* amask  = (const float*)d_in[2];
  const float* qkvw   = (const float*)d_in[3];
  const float* outw   = (const float*)d_in[4];
  float* out = (float*)d_out;

  float* cosT = (float*)d_ws;                  // 4096*32
  float* sinT = cosT + S_LEN * 32;             // 4096*32
  float* qkv  = sinT + S_LEN * 32;             // 2304*4096
  float* attn = qkv + (size_t)MQKV * S_LEN;    // 768*4096   (total ~51 MB)

  rope_table_kernel<<<(S_LEN * 32 + 255) / 256, 256, 0, stream>>>(pos, cosT, sinT);
  gemm_rope_kernel<<<dim3(64, 36), 256, 0, stream>>>(qkvw, x, qkv, cosT, sinT, 24);
  attn_kernel<<<dim3(64, 12), 256, 0, stream>>>(qkv, amask, attn);
  gemm_rope_kernel<<<dim3(64, 12), 256, 0, stream>>>(outw, attn, out, cosT, sinT, 0);
}

// Round 3
// 203.423 us; speedup vs baseline: 2.4007x; 2.4007x over previous
//
#include <hip/hip_runtime.h>
#include <hip/hip_bf16.h>
#include <math.h>

#define S_LEN 4096

typedef unsigned short u16t;
typedef unsigned int u32t;
typedef __attribute__((ext_vector_type(8))) short bf16x8;
typedef __attribute__((ext_vector_type(4))) float f32x4;

__device__ __forceinline__ u16t f2bf_u16(float f) {
  union { __hip_bfloat16 h; u16t u; } r; r.h = __float2bfloat16(f); return r.u;
}
__device__ __forceinline__ u32t pack_bf(float a, float b) {
  return (u32t)f2bf_u16(a) | ((u32t)f2bf_u16(b) << 16);
}
__device__ __forceinline__ float bf_lo(u32t u) { union { u32t x; float f; } t; t.x = u << 16; return t.f; }
__device__ __forceinline__ float bf_hi(u32t u) { union { u32t x; float f; } t; t.x = u & 0xffff0000u; return t.f; }

__device__ __forceinline__ float dot2bf(u32t a, u32t b, float acc) {
#if __has_builtin(__builtin_amdgcn_fdot2_f32_bf16)
  typedef __attribute__((ext_vector_type(2))) __bf16 bf16x2_t;
  union { u32t u; bf16x2_t v; } ua, ub; ua.u = a; ub.u = b;
  return __builtin_amdgcn_fdot2_f32_bf16(ua.v, ub.v, acc, false);
#else
  return acc + bf_lo(a) * bf_lo(b) + bf_hi(a) * bf_hi(b);
#endif
}

// ---------------- RoPE table, layout [32 freq][4096 s] ----------------
__global__ __launch_bounds__(256) void rope_table_kernel(
    const int* __restrict__ pos, float* __restrict__ cosT, float* __restrict__ sinT)
{
  int idx = blockIdx.x * 256 + threadIdx.x;
  if (idx >= 32 * S_LEN) return;
  int j = idx >> 12, s = idx & 4095;
  double p = (double)pos[s];
  double inv = exp(-((double)(2 * j) / 64.0) * log(10000.0));
  double a = p * inv;
  cosT[idx] = (float)cos(a);
  sinT[idx] = (float)sin(a);
}

// ---------------- flat f32 -> bf16 cast (n4 float4's) ----------------
__global__ __launch_bounds__(256) void castw_kernel(
    const float* __restrict__ src, u16t* __restrict__ dst, int n4)
{
  int i = blockIdx.x * 256 + threadIdx.x;
  if (i >= n4) return;
  float4 v = ((const float4*)src)[i];
  union { u16t h[4]; uint2 u; } r;
  r.h[0] = f2bf_u16(v.x); r.h[1] = f2bf_u16(v.y);
  r.h[2] = f2bf_u16(v.z); r.h[3] = f2bf_u16(v.w);
  ((uint2*)dst)[i] = r.u;
}

// ---------------- x [768][4096] f32 -> xT [4096][768] bf16 ----------------
__global__ __launch_bounds__(256) void tcast_kernel(
    const float* __restrict__ x, u16t* __restrict__ xT)
{
  __shared__ float T[64][65];
  int s0 = blockIdx.x * 64, c0 = blockIdx.y * 64;
  int sl = threadIdx.x & 63, g = threadIdx.x >> 6;
#pragma unroll
  for (int r = 0; r < 16; ++r) {
    int cl = g + 4 * r;
    T[cl][sl] = x[(size_t)(c0 + cl) * S_LEN + s0 + sl];
  }
  __syncthreads();
  int cl2 = threadIdx.x & 63;
#pragma unroll
  for (int r = 0; r < 16; ++r) {
    int sl2 = g + 4 * r;
    xT[(size_t)(s0 + sl2) * 768 + c0 + cl2] = f2bf_u16(T[cl2][sl2]);
  }
}

// ---------------- bf16 MFMA GEMM, 128x128 tile, BK=64 ----------------
// A [M][768] bf16 row-major, Bt [4096][768] bf16 row-major (pre-transposed B).
// C[m][n] = sum_k A[m][k]*Bt[n][k]. Rope epilogue for m < ropeRows.
template <int WRITE_BF16>
__global__ __launch_bounds__(256) void gemm_kernel(
    const u16t* __restrict__ A, const u16t* __restrict__ Bt, void* __restrict__ Cv,
    const float* __restrict__ cosT, const float* __restrict__ sinT, int ropeRows)
{
  __shared__ u16t Al[128 * 64];
  __shared__ u16t Bl[128 * 64];
  const int t = threadIdx.x;
  const int m0 = blockIdx.y * 128, n0 = blockIdx.x * 128;
  const int lane = t & 63, w = t >> 6;
  const int wr = w >> 1, wc = w & 1;

  f32x4 acc[4][4];
#pragma unroll
  for (int i = 0; i < 4; ++i)
#pragma unroll
    for (int j = 0; j < 4; ++j) acc[i][j] = (f32x4){0.f, 0.f, 0.f, 0.f};

  uint4 pa[4], pb[4];
#pragma unroll
  for (int cc = 0; cc < 4; ++cc) {
    int q = cc * 256 + t, row = q >> 3, slot = q & 7;
    pa[cc] = *(const uint4*)(A + (size_t)(m0 + row) * 768 + slot * 8);
    pb[cc] = *(const uint4*)(Bt + (size_t)(n0 + row) * 768 + slot * 8);
  }
  for (int kt = 0; kt < 12; ++kt) {
    __syncthreads();
#pragma unroll
    for (int cc = 0; cc < 4; ++cc) {
      int q = cc * 256 + t, row = q >> 3, slot = q & 7;
      int sw = slot ^ (row & 7);
      *(uint4*)&Al[row * 64 + sw * 8] = pa[cc];
      *(uint4*)&Bl[row * 64 + sw * 8] = pb[cc];
    }
    __syncthreads();
    if (kt < 11) {
      int ko = (kt + 1) * 64;
#pragma unroll
      for (int cc = 0; cc < 4; ++cc) {
        int q = cc * 256 + t, row = q >> 3, slot = q & 7;
        pa[cc] = *(const uint4*)(A + (size_t)(m0 + row) * 768 + ko + slot * 8);
        pb[cc] = *(const uint4*)(Bt + (size_t)(n0 + row) * 768 + ko + slot * 8);
      }
    }
#pragma unroll
    for (int kh = 0; kh < 2; ++kh) {
      bf16x8 af[4], bg[4];
#pragma unroll
      for (int f = 0; f < 4; ++f) {
        int ra = wr * 64 + f * 16 + (lane & 15);
        int sa = (kh * 4 + (lane >> 4)) ^ (ra & 7);
        af[f] = *(const bf16x8*)&Al[ra * 64 + sa * 8];
        int rb = wc * 64 + f * 16 + (lane & 15);
        int sb = (kh * 4 + (lane >> 4)) ^ (rb & 7);
        bg[f] = *(const bf16x8*)&Bl[rb * 64 + sb * 8];
      }
#pragma unroll
      for (int i = 0; i < 4; ++i)
#pragma unroll
        for (int j = 0; j < 4; ++j)
          acc[i][j] = __builtin_amdgcn_mfma_f32_16x16x32_bf16(af[i], bg[j], acc[i][j], 0, 0, 0);
    }
  }

  const int mq = m0 + wr * 64;  // 64-aligned quadrant base (one head)
  if (mq < ropeRows) {
#pragma unroll
    for (int j4 = 0; j4 < 4; ++j4)
#pragma unroll
      for (int nf = 0; nf < 4; ++nf) {
        int n = n0 + wc * 64 + nf * 16 + (lane & 15);
#pragma unroll
        for (int p = 0; p < 2; ++p) {
          int fidx = p * 16 + (lane >> 4) * 4 + j4;
          float cc = cosT[fidx * S_LEN + n], ss = sinT[fidx * S_LEN + n];
          float lo = acc[p][nf][j4], hi = acc[p + 2][nf][j4];
          acc[p][nf][j4]     = lo * cc - hi * ss;
          acc[p + 2][nf][j4] = hi * cc + lo * ss;
        }
      }
  }
#pragma unroll
  for (int i = 0; i < 4; ++i)
#pragma unroll
    for (int j4 = 0; j4 < 4; ++j4) {
      int m = mq + i * 16 + (lane >> 4) * 4 + j4;
#pragma unroll
      for (int nf = 0; nf < 4; ++nf) {
        int n = n0 + wc * 64 + nf * 16 + (lane & 15);
        float v = acc[i][nf][j4];
        if (WRITE_BF16) ((u16t*)Cv)[(size_t)m * S_LEN + n] = f2bf_u16(v);
        else            ((float*)Cv)[(size_t)m * S_LEN + n] = v;
      }
    }
}

// ---------------- windowed attention ----------------
// qkvb bf16 [2304][4096]; writes attnT bf16 [4096][768].
#define QB 64
#define KS 192
#define KLD 68
#define PLD 196

__global__ __launch_bounds__(256) void attn_kernel(
    const u16t* __restrict__ qkvb, const float* __restrict__ amask,
    u16t* __restrict__ attnT)
{
  __shared__ u16t KV[KS * KLD];   // K rows [kk][d]; later reused as Vt [d][kk] (PLD stride)
  __shared__ u16t Pl[QB * PLD];   // P bf16 [qi][kk]
  __shared__ float red[QB][4];
  __shared__ float red2[QB][4];

  const int t = threadIdx.x;
  const int h = blockIdx.y;
  const int q0 = blockIdx.x * QB;
  const int kstart = q0 - 64;
  const u16t* qbase = qkvb + (size_t)(h * 64) * S_LEN;
  const u16t* kbase = qkvb + (size_t)(768 + h * 64) * S_LEN;
  const u16t* vbase = qkvb + (size_t)(1536 + h * 64) * S_LEN;

  // stage K: dword = keys (2c, 2c+1) of dim d
  for (int ii = t; ii < 64 * 96; ii += 256) {
    int d = ii / 96, c = ii - d * 96;
    int key0 = kstart + 2 * c;
    u32t v = 0;
    if (key0 >= 0 && key0 < S_LEN) v = *(const u32t*)(kbase + (size_t)d * S_LEN + key0);
    KV[(2 * c) * KLD + d]     = (u16t)(v & 0xffffu);
    KV[(2 * c + 1) * KLD + d] = (u16t)(v >> 16);
  }
  // Q row into regs (packed bf16 pairs along d)
  const int qi = t & 63, part = t >> 6;
  u32t Qp[32];
#pragma unroll
  for (int c = 0; c < 32; ++c) {
    u32t lo = qbase[(size_t)(2 * c) * S_LEN + q0 + qi];
    u32t hi = qbase[(size_t)(2 * c + 1) * S_LEN + q0 + qi];
    Qp[c] = lo | (hi << 16);
  }
  __syncthreads();

  // scores: thread (qi, part) covers kk in [part*48, part*48+48)
  float sc[48];
  const int kb = part * 48;
#pragma unroll
  for (int kk = 0; kk < 48; ++kk) {
    int kkk = kb + kk;
    float s = 0.f;
    const u16t* krow = &KV[kkk * KLD];
#pragma unroll
    for (int c2 = 0; c2 < 16; ++c2) {
      uint2 kw = *(const uint2*)(krow + 4 * c2);
      s = dot2bf(Qp[2 * c2], kw.x, s);
      s = dot2bf(Qp[2 * c2 + 1], kw.y, s);
    }
    int key = kstart + kkk;
    bool inw = (key >= 0) && (key < S_LEN) && (kkk >= qi) && (kkk <= qi + 128);
    sc[kk] = inw ? (s * 0.125f + amask[(size_t)(q0 + qi) * S_LEN + key]) : -3.0e38f;
  }
  float m = sc[0];
#pragma unroll
  for (int kk = 1; kk < 48; ++kk) m = fmaxf(m, sc[kk]);
  red[qi][part] = m;
  __syncthreads();

  // V global loads issued early (hide under exp), written after exp
  u32t vstage[24];
#pragma unroll
  for (int jj = 0; jj < 24; ++jj) {
    int ii = t + jj * 256;
    int d = ii / 96, c = ii - d * 96;
    int key0 = kstart + 2 * c;
    vstage[jj] = (key0 >= 0 && key0 < S_LEN) ? *(const u32t*)(vbase + (size_t)d * S_LEN + key0) : 0u;
  }
  float rm = fmaxf(fmaxf(red[qi][0], red[qi][1]), fmaxf(red[qi][2], red[qi][3]));
  float psum = 0.f;
#pragma unroll
  for (int c = 0; c < 24; ++c) {
    float e0 = __expf(sc[2 * c] - rm);
    float e1 = __expf(sc[2 * c + 1] - rm);
    psum += e0 + e1;
    *(u32t*)&Pl[qi * PLD + kb + 2 * c] = pack_bf(e0, e1);
  }
  red2[qi][part] = psum;
  // write Vt[d][kk] over KV
#pragma unroll
  for (int jj = 0; jj < 24; ++jj) {
    int ii = t + jj * 256;
    int d = ii / 96, c = ii - d * 96;
    *(u32t*)&KV[d * PLD + 2 * c] = vstage[jj];
  }
  __syncthreads();

  // PV: thread (d = t&63, dpart = t>>6) -> 16 queries
  const int d = t & 63, dpart = t >> 6;
  float acc[16];
#pragma unroll
  for (int j = 0; j < 16; ++j) acc[j] = 0.f;
  for (int cb = 0; cb < 6; ++cb) {
    uint2 vb[8];
#pragma unroll
    for (int u = 0; u < 8; ++u)
      vb[u] = *(const uint2*)&KV[d * PLD + 4 * (8 * cb + u)];
#pragma unroll
    for (int j = 0; j < 16; ++j) {
      const u16t* prow = &Pl[(dpart * 16 + j) * PLD + 32 * cb];
#pragma unroll
      for (int u = 0; u < 8; ++u) {
        uint2 pw = *(const uint2*)(prow + 4 * u);
        acc[j] = dot2bf(pw.x, vb[u].x, acc[j]);
        acc[j] = dot2bf(pw.y, vb[u].y, acc[j]);
      }
    }
  }
#pragma unroll
  for (int j = 0; j < 16; ++j) {
    int qr = dpart * 16 + j;
    float inv = 1.f / (red2[qr][0] + red2[qr][1] + red2[qr][2] + red2[qr][3]);
    attnT[(size_t)(q0 + qr) * 768 + h * 64 + d] = f2bf_u16(acc[j] * inv);
  }
}

extern "C" void kernel_launch(void* const* d_in, const int* in_sizes, int n_in,
                              void* d_out, int out_size, void* d_ws, size_t ws_size,
                              hipStream_t stream) {
  const float* x     = (const float*)d_in[0];
  const int*   pos   = (const int*)d_in[1];
  const float* amask = (const float*)d_in[2];
  const float* qkvw  = (const float*)d_in[3];
  const float* outw  = (const float*)d_in[4];
  float* out = (float*)d_out;

  char* ws = (char*)d_ws;
  float* cosT   = (float*)ws;                          ws += 32 * S_LEN * 4;
  float* sinT   = (float*)ws;                          ws += 32 * S_LEN * 4;
  u16t*  xT     = (u16t*)ws;                           ws += (size_t)S_LEN * 768 * 2;
  u16t*  wq_bf  = (u16t*)ws;                           ws += (size_t)2304 * 768 * 2;
  u16t*  wo_bf  = (u16t*)ws;                           ws += (size_t)768 * 768 * 2;
  u16t*  qkv_bf = (u16t*)ws;                           ws += (size_t)2304 * S_LEN * 2;
  u16t*  attnT  = (u16t*)ws;

  rope_table_kernel<<<(32 * S_LEN) / 256, 256, 0, stream>>>(pos, cosT, sinT);
  castw_kernel<<<(2304 * 768 / 4) / 256, 256, 0, stream>>>(qkvw, wq_bf, 2304 * 768 / 4);
  castw_kernel<<<(768 * 768 / 4) / 256, 256, 0, stream>>>(outw, wo_bf, 768 * 768 / 4);
  tcast_kernel<<<dim3(64, 12), 256, 0, stream>>>(x, xT);
  gemm_kernel<1><<<dim3(32, 18), 256, 0, stream>>>(wq_bf, xT, qkv_bf, cosT, sinT, 1536);
  attn_kernel<<<dim3(64, 12), 256, 0, stream>>>(qkv_bf, amask, attnT);
  gemm_kernel<0><<<dim3(32, 6), 256, 0, stream>>>(wo_bf, attnT, out, cosT, sinT, 0);
}

// Round 4
// 120.471 us; speedup vs baseline: 4.0538x; 1.6886x over previous
//
#include <hip/hip_runtime.h>
#include <hip/hip_bf16.h>
#include <math.h>

#define S_LEN 4096

typedef unsigned short u16t;
typedef unsigned int u32t;
typedef __attribute__((ext_vector_type(8))) short bf16x8;
typedef __attribute__((ext_vector_type(4))) float f32x4;

__device__ __forceinline__ u16t f2bf_u16(float f) {
  union { __hip_bfloat16 h; u16t u; } r; r.h = __float2bfloat16(f); return r.u;
}
__device__ __forceinline__ u32t pack_bf(float a, float b) {
  return (u32t)f2bf_u16(a) | ((u32t)f2bf_u16(b) << 16);
}
__device__ __forceinline__ float bf_lo(u32t u) { union { u32t x; float f; } t; t.x = u << 16; return t.f; }
__device__ __forceinline__ float bf_hi(u32t u) { union { u32t x; float f; } t; t.x = u & 0xffff0000u; return t.f; }

__device__ __forceinline__ float dot2bf(u32t a, u32t b, float acc) {
#if __has_builtin(__builtin_amdgcn_fdot2_f32_bf16)
  typedef __attribute__((ext_vector_type(2))) __bf16 bf16x2_t;
  union { u32t u; bf16x2_t v; } ua, ub; ua.u = a; ub.u = b;
  return __builtin_amdgcn_fdot2_f32_bf16(ua.v, ub.v, acc, false);
#else
  return acc + bf_lo(a) * bf_lo(b) + bf_hi(a) * bf_hi(b);
#endif
}

// async global->LDS, 16B per lane; LDS dest = wave-uniform base + lane*16
__device__ __forceinline__ void stage16(const u16t* g, u16t* l) {
  __builtin_amdgcn_global_load_lds(
      (const __attribute__((address_space(1))) void*)g,
      (__attribute__((address_space(3))) void*)l, 16, 0, 0);
}

// ---------------- RoPE table, layout [32 freq][4096 s] ----------------
__global__ __launch_bounds__(256) void rope_table_kernel(
    const int* __restrict__ pos, float* __restrict__ cosT, float* __restrict__ sinT)
{
  int idx = blockIdx.x * 256 + threadIdx.x;
  if (idx >= 32 * S_LEN) return;
  int j = idx >> 12, s = idx & 4095;
  double p = (double)pos[s];
  double inv = exp(-((double)(2 * j) / 64.0) * log(10000.0));
  double a = p * inv;
  cosT[idx] = (float)cos(a);
  sinT[idx] = (float)sin(a);
}

// ---------------- flat f32 -> bf16 cast (n4 float4's) ----------------
__global__ __launch_bounds__(256) void castw_kernel(
    const float* __restrict__ src, u16t* __restrict__ dst, int n4)
{
  int i = blockIdx.x * 256 + threadIdx.x;
  if (i >= n4) return;
  float4 v = ((const float4*)src)[i];
  union { u16t h[4]; uint2 u; } r;
  r.h[0] = f2bf_u16(v.x); r.h[1] = f2bf_u16(v.y);
  r.h[2] = f2bf_u16(v.z); r.h[3] = f2bf_u16(v.w);
  ((uint2*)dst)[i] = r.u;
}

// ---------------- x [768][4096] f32 -> xT [4096][768] bf16 ----------------
__global__ __launch_bounds__(256) void tcast_kernel(
    const float* __restrict__ x, u16t* __restrict__ xT)
{
  __shared__ float T[64][65];
  int s0 = blockIdx.x * 64, c0 = blockIdx.y * 64;
  int sl = threadIdx.x & 63, g = threadIdx.x >> 6;
#pragma unroll
  for (int r = 0; r < 16; ++r) {
    int cl = g + 4 * r;
    T[cl][sl] = x[(size_t)(c0 + cl) * S_LEN + s0 + sl];
  }
  __syncthreads();
  int cl2 = threadIdx.x & 63;
#pragma unroll
  for (int r = 0; r < 16; ++r) {
    int sl2 = g + 4 * r;
    xT[(size_t)(s0 + sl2) * 768 + c0 + cl2] = f2bf_u16(T[cl2][sl2]);
  }
}

// ---------------- bf16 MFMA GEMM, 128x128 tile, BK=64, gload_lds 2-phase ----
// A [M][768] bf16 row-major, Bt [4096][768] bf16 row-major (pre-transposed B).
// C[m][n] = sum_k A[m][k]*Bt[n][k]. Rope epilogue for m < ropeRows.
// LDS image slot s of row r holds global chunk s ^ (r&7)  (T2 swizzle via
// pre-swizzled global source; identical image to the round-2 ds_write path).
template <int WRITE_BF16>
__global__ __launch_bounds__(256) void gemm_kernel(
    const u16t* __restrict__ A, const u16t* __restrict__ Bt, void* __restrict__ Cv,
    const float* __restrict__ cosT, const float* __restrict__ sinT, int ropeRows,
    int tilesX, int tilesAll)
{
  __shared__ __align__(16) u16t smem[32768];   // [2 buf][A 8192 | B 8192] = 64 KB
  const int t = threadIdx.x;
  const int lane = t & 63, w = t >> 6;
  const int wr = w >> 1, wc = w & 1;

  // T1: XCD-chunked bijective remap (tilesAll % 8 == 0)
  const int cpx = tilesAll >> 3;
  const int nid = (blockIdx.x & 7) * cpx + (blockIdx.x >> 3);
  const int m0 = (nid / tilesX) * 128, n0 = (nid % tilesX) * 128;

  f32x4 acc[4][4];
#pragma unroll
  for (int i = 0; i < 4; ++i)
#pragma unroll
    for (int j = 0; j < 4; ++j) acc[i][j] = (f32x4){0.f, 0.f, 0.f, 0.f};

  // per-lane pre-swizzled global source (r&7 == lane>>3 for all staged rows)
  const int rsub = w * 8 + (lane >> 3);                 // row within 32-row group
  const int csw  = ((lane & 7) ^ (lane >> 3)) * 8;      // swizzled u16 chunk
  const u16t* gA = A  + (size_t)(m0 + rsub) * 768 + csw;
  const u16t* gB = Bt + (size_t)(n0 + rsub) * 768 + csw;
  u16t* lb0 = smem;
  u16t* lb1 = smem + 16384;

  // prologue stage of K-tile 0
#pragma unroll
  for (int cc = 0; cc < 4; ++cc) {
    stage16(gA + (size_t)cc * (32 * 768), lb0 + (cc * 32 + w * 8) * 64);
    stage16(gB + (size_t)cc * (32 * 768), lb0 + 8192 + (cc * 32 + w * 8) * 64);
  }
  asm volatile("s_waitcnt vmcnt(0)" ::: "memory");
  __builtin_amdgcn_s_barrier();
  __builtin_amdgcn_sched_barrier(0);

  for (int kt = 0; kt < 12; ++kt) {
    u16t* cur = (kt & 1) ? lb1 : lb0;
    u16t* nxt = (kt & 1) ? lb0 : lb1;
    if (kt < 11) {
      const u16t* pA = gA + (kt + 1) * 64;
      const u16t* pB = gB + (kt + 1) * 64;
#pragma unroll
      for (int cc = 0; cc < 4; ++cc) {
        stage16(pA + (size_t)cc * (32 * 768), nxt + (cc * 32 + w * 8) * 64);
        stage16(pB + (size_t)cc * (32 * 768), nxt + 8192 + (cc * 32 + w * 8) * 64);
      }
    }
#pragma unroll
    for (int kh = 0; kh < 2; ++kh) {
      bf16x8 af[4], bg[4];
#pragma unroll
      for (int f = 0; f < 4; ++f) {
        int ra = wr * 64 + f * 16 + (lane & 15);
        int rb = wc * 64 + f * 16 + (lane & 15);
        int sg = ((kh * 4 + (lane >> 4)) ^ (lane & 7)) * 8;
        af[f] = *(const bf16x8*)(cur + ra * 64 + sg);
        bg[f] = *(const bf16x8*)(cur + 8192 + rb * 64 + sg);
      }
#pragma unroll
      for (int i = 0; i < 4; ++i)
#pragma unroll
        for (int j = 0; j < 4; ++j)
          acc[i][j] = __builtin_amdgcn_mfma_f32_16x16x32_bf16(af[i], bg[j], acc[i][j], 0, 0, 0);
    }
    asm volatile("s_waitcnt vmcnt(0)" ::: "memory");
    __builtin_amdgcn_s_barrier();
    __builtin_amdgcn_sched_barrier(0);
  }

  // RoPE epilogue (in regs); quadrant base mq is 64-aligned = one head
  const int mq = m0 + wr * 64;
  if (mq < ropeRows) {
#pragma unroll
    for (int j4 = 0; j4 < 4; ++j4)
#pragma unroll
      for (int nf = 0; nf < 4; ++nf) {
        int n = n0 + wc * 64 + nf * 16 + (lane & 15);
#pragma unroll
        for (int p = 0; p < 2; ++p) {
          int fidx = p * 16 + (lane >> 4) * 4 + j4;
          float cc = cosT[fidx * S_LEN + n], ss = sinT[fidx * S_LEN + n];
          float lo = acc[p][nf][j4], hi = acc[p + 2][nf][j4];
          acc[p][nf][j4]     = lo * cc - hi * ss;
          acc[p + 2][nf][j4] = hi * cc + lo * ss;
        }
      }
  }

  // coalesced C store via LDS
  __syncthreads();   // all MFMA reads of smem done (loop barrier), safe to reuse
  if (WRITE_BF16) {
    u16t* Cs = smem;   // [128][128] u16 = 32 KB
#pragma unroll
    for (int i = 0; i < 4; ++i)
#pragma unroll
      for (int j4 = 0; j4 < 4; ++j4) {
        int mrow = wr * 64 + i * 16 + (lane >> 4) * 4 + j4;
#pragma unroll
        for (int nf = 0; nf < 4; ++nf) {
          int col = wc * 64 + nf * 16 + (lane & 15);
          Cs[mrow * 128 + col] = f2bf_u16(acc[i][nf][j4]);
        }
      }
    __syncthreads();
    u16t* Co = (u16t*)Cv;
#pragma unroll
    for (int it = 0; it < 8; ++it) {
      int idx = it * 256 + t;
      int row = idx >> 4, ch = idx & 15;
      *(uint4*)&Co[(size_t)(m0 + row) * S_LEN + n0 + ch * 8] =
          *(const uint4*)&Cs[row * 128 + ch * 8];
    }
  } else {
    float* Cs = (float*)smem;  // [128][128] f32 = 64 KB
#pragma unroll
    for (int i = 0; i < 4; ++i)
#pragma unroll
      for (int j4 = 0; j4 < 4; ++j4) {
        int mrow = wr * 64 + i * 16 + (lane >> 4) * 4 + j4;
#pragma unroll
        for (int nf = 0; nf < 4; ++nf) {
          int col = wc * 64 + nf * 16 + (lane & 15);
          Cs[mrow * 128 + col] = acc[i][nf][j4];
        }
      }
    __syncthreads();
    float* Co = (float*)Cv;
#pragma unroll
    for (int it = 0; it < 16; ++it) {
      int idx = it * 256 + t;
      int row = idx >> 5, ch = idx & 31;
      *(float4*)&Co[(size_t)(m0 + row) * S_LEN + n0 + ch * 4] =
          *(const float4*)&Cs[row * 128 + ch * 4];
    }
  }
}

// ---------------- windowed attention (unchanged from round 2) ----------------
#define QB 64
#define KS 192
#define KLD 68
#define PLD 196

__global__ __launch_bounds__(256) void attn_kernel(
    const u16t* __restrict__ qkvb, const float* __restrict__ amask,
    u16t* __restrict__ attnT)
{
  __shared__ u16t KV[KS * KLD];
  __shared__ u16t Pl[QB * PLD];
  __shared__ float red[QB][4];
  __shared__ float red2[QB][4];

  const int t = threadIdx.x;
  const int h = blockIdx.y;
  const int q0 = blockIdx.x * QB;
  const int kstart = q0 - 64;
  const u16t* qbase = qkvb + (size_t)(h * 64) * S_LEN;
  const u16t* kbase = qkvb + (size_t)(768 + h * 64) * S_LEN;
  const u16t* vbase = qkvb + (size_t)(1536 + h * 64) * S_LEN;

  for (int ii = t; ii < 64 * 96; ii += 256) {
    int d = ii / 96, c = ii - d * 96;
    int key0 = kstart + 2 * c;
    u32t v = 0;
    if (key0 >= 0 && key0 < S_LEN) v = *(const u32t*)(kbase + (size_t)d * S_LEN + key0);
    KV[(2 * c) * KLD + d]     = (u16t)(v & 0xffffu);
    KV[(2 * c + 1) * KLD + d] = (u16t)(v >> 16);
  }
  const int qi = t & 63, part = t >> 6;
  u32t Qp[32];
#pragma unroll
  for (int c = 0; c < 32; ++c) {
    u32t lo = qbase[(size_t)(2 * c) * S_LEN + q0 + qi];
    u32t hi = qbase[(size_t)(2 * c + 1) * S_LEN + q0 + qi];
    Qp[c] = lo | (hi << 16);
  }
  __syncthreads();

  float sc[48];
  const int kb = part * 48;
#pragma unroll
  for (int kk = 0; kk < 48; ++kk) {
    int kkk = kb + kk;
    float s = 0.f;
    const u16t* krow = &KV[kkk * KLD];
#pragma unroll
    for (int c2 = 0; c2 < 16; ++c2) {
      uint2 kw = *(const uint2*)(krow + 4 * c2);
      s = dot2bf(Qp[2 * c2], kw.x, s);
      s = dot2bf(Qp[2 * c2 + 1], kw.y, s);
    }
    int key = kstart + kkk;
    bool inw = (key >= 0) && (key < S_LEN) && (kkk >= qi) && (kkk <= qi + 128);
    sc[kk] = inw ? (s * 0.125f + amask[(size_t)(q0 + qi) * S_LEN + key]) : -3.0e38f;
  }
  float m = sc[0];
#pragma unroll
  for (int kk = 1; kk < 48; ++kk) m = fmaxf(m, sc[kk]);
  red[qi][part] = m;
  __syncthreads();

  u32t vstage[24];
#pragma unroll
  for (int jj = 0; jj < 24; ++jj) {
    int ii = t + jj * 256;
    int d = ii / 96, c = ii - d * 96;
    int key0 = kstart + 2 * c;
    vstage[jj] = (key0 >= 0 && key0 < S_LEN) ? *(const u32t*)(vbase + (size_t)d * S_LEN + key0) : 0u;
  }
  float rm = fmaxf(fmaxf(red[qi][0], red[qi][1]), fmaxf(red[qi][2], red[qi][3]));
  float psum = 0.f;
#pragma unroll
  for (int c = 0; c < 24; ++c) {
    float e0 = __expf(sc[2 * c] - rm);
    float e1 = __expf(sc[2 * c + 1] - rm);
    psum += e0 + e1;
    *(u32t*)&Pl[qi * PLD + kb + 2 * c] = pack_bf(e0, e1);
  }
  red2[qi][part] = psum;
#pragma unroll
  for (int jj = 0; jj < 24; ++jj) {
    int ii = t + jj * 256;
    int d = ii / 96, c = ii - d * 96;
    *(u32t*)&KV[d * PLD + 2 * c] = vstage[jj];
  }
  __syncthreads();

  const int d = t & 63, dpart = t >> 6;
  float acc[16];
#pragma unroll
  for (int j = 0; j < 16; ++j) acc[j] = 0.f;
  for (int cb = 0; cb < 6; ++cb) {
    uint2 vb[8];
#pragma unroll
    for (int u = 0; u < 8; ++u)
      vb[u] = *(const uint2*)&KV[d * PLD + 4 * (8 * cb + u)];
#pragma unroll
    for (int j = 0; j < 16; ++j) {
      const u16t* prow = &Pl[(dpart * 16 + j) * PLD + 32 * cb];
#pragma unroll
      for (int u = 0; u < 8; ++u) {
        uint2 pw = *(const uint2*)(prow + 4 * u);
        acc[j] = dot2bf(pw.x, vb[u].x, acc[j]);
        acc[j] = dot2bf(pw.y, vb[u].y, acc[j]);
      }
    }
  }
#pragma unroll
  for (int j = 0; j < 16; ++j) {
    int qr = dpart * 16 + j;
    float inv = 1.f / (red2[qr][0] + red2[qr][1] + red2[qr][2] + red2[qr][3]);
    attnT[(size_t)(q0 + qr) * 768 + h * 64 + d] = f2bf_u16(acc[j] * inv);
  }
}

extern "C" void kernel_launch(void* const* d_in, const int* in_sizes, int n_in,
                              void* d_out, int out_size, void* d_ws, size_t ws_size,
                              hipStream_t stream) {
  const float* x     = (const float*)d_in[0];
  const int*   pos   = (const int*)d_in[1];
  const float* amask = (const float*)d_in[2];
  const float* qkvw  = (const float*)d_in[3];
  const float* outw  = (const float*)d_in[4];
  float* out = (float*)d_out;

  char* ws = (char*)d_ws;
  float* cosT   = (float*)ws;                          ws += 32 * S_LEN * 4;
  float* sinT   = (float*)ws;                          ws += 32 * S_LEN * 4;
  u16t*  xT     = (u16t*)ws;                           ws += (size_t)S_LEN * 768 * 2;
  u16t*  wq_bf  = (u16t*)ws;                           ws += (size_t)2304 * 768 * 2;
  u16t*  wo_bf  = (u16t*)ws;                           ws += (size_t)768 * 768 * 2;
  u16t*  qkv_bf = (u16t*)ws;                           ws += (size_t)2304 * S_LEN * 2;
  u16t*  attnT  = (u16t*)ws;

  rope_table_kernel<<<(32 * S_LEN) / 256, 256, 0, stream>>>(pos, cosT, sinT);
  castw_kernel<<<(2304 * 768 / 4) / 256, 256, 0, stream>>>(qkvw, wq_bf, 2304 * 768 / 4);
  castw_kernel<<<(768 * 768 / 4) / 256, 256, 0, stream>>>(outw, wo_bf, 768 * 768 / 4);
  tcast_kernel<<<dim3(64, 12), 256, 0, stream>>>(x, xT);
  gemm_kernel<1><<<576, 256, 0, stream>>>(wq_bf, xT, qkv_bf, cosT, sinT, 1536, 32, 576);
  attn_kernel<<<dim3(64, 12), 256, 0, stream>>>(qkv_bf, amask, attnT);
  gemm_kernel<0><<<192, 256, 0, stream>>>(wo_bf, attnT, out, cosT, sinT, 0, 32, 192);
}